// Round 3
// baseline (46.316 us; speedup 1.0000x reference)
//
#include <hip/hip_runtime.h>

// Kronecker product: out[i*64+p, j*64+q] = A[i,j] * B[p,q]
// A: 128x128 f32, B: 64x64 f32, out: 8192x8192 f32 (256 MB) -> write-BW bound.
// One float4 store per thread, exact grid, nontemporal stores.

constexpr int Ac = 128;
constexpr int Bc = 64;

typedef float f32x4 __attribute__((ext_vector_type(4)));  // native vector: nontemporal-store-legal

__global__ __launch_bounds__(256) void kron_kernel(
    const float* __restrict__ A,
    const float* __restrict__ B,
    float* __restrict__ out,
    int total4)
{
    const int idx = blockIdx.x * 256 + threadIdx.x;
    if (idx >= total4) return;

    const int r  = idx >> 11;      // output row (2048 float4 per row)
    const int c4 = idx & 2047;     // float4 index within row
    const int c  = c4 << 2;        // float column

    const float a  = A[(r >> 6) * Ac + (c >> 6)];                              // L1/L2-hit
    const f32x4 b4 = *reinterpret_cast<const f32x4*>(&B[(r & 63) * Bc + (c & 63)]); // L1-hit

    const f32x4 o = a * b4;
    __builtin_nontemporal_store(o, reinterpret_cast<f32x4*>(out) + idx);       // streaming store (nt)
}

extern "C" void kernel_launch(void* const* d_in, const int* in_sizes, int n_in,
                              void* d_out, int out_size, void* d_ws, size_t ws_size,
                              hipStream_t stream)
{
    const float* A = (const float*)d_in[0];
    const float* B = (const float*)d_in[1];
    float* out = (float*)d_out;

    const int total4 = out_size / 4;               // 16,777,216 float4 stores
    const int block = 256;
    const int grid = (total4 + block - 1) / block; // 65,536 blocks, exact

    kron_kernel<<<grid, block, 0, stream>>>(A, B, out, total4);
}